// Round 3
// baseline (436.382 us; speedup 1.0000x reference)
//
#include <hip/hip_runtime.h>
#include <math.h>

// RoPE over x[4,32,4096,128] fp32. out[2i] = cos*x[2i]-sin*x[2i+1]; out[2i+1] = sin*x[2i]+cos*x[2i+1]
// a(s,i) = pos[s] * theta^(-i/64), i in [0,64).
//
// v3: single dispatch (v2's serialized table-build dispatch cost +20 us and bought
// nothing -- trig throughput ceiling is ~250 TB/s-equivalent, 40x above HBM).
// Each thread handles 4 float4s at stride T = n4/4. T is a multiple of the
// 131072-float4 angle period (one (b,h) slice), so all 4 offsets share the same
// (s, pair) -> ONE set of trig serves 4 rotations, and the 4 nontemporal loads
// are all in flight before the first use (latency hiding / BW share vs the
// harness's concurrent poison fills).
//
// Timing model (confirmed r0 vs r2): dur_us ~= 2 x 165us harness fills + kernel.
// Kernel floor: 512 MiB @ ~6.3-6.5 TB/s => ~83 us.

typedef float f32x4 __attribute__((ext_vector_type(4)));

#define THETA_LOG2_OVER_HALF 0.20762050593046013f   // log2(10000)/64
#define FREQ_STEP 0.8659643233600653f               // 10000^(-1/64)

#define SEQ 4096
#define ROW_F4 32                       // 128 floats per row = 32 float4
#define PERIOD_F4 (SEQ * ROW_F4)        // 131072 float4 = one (b,h) slice

// ---------------- v3: streaming rotate, inline trig, 4 float4/thread ----------------
__global__ __launch_bounds__(256) void rope_f32_x4_kernel(
    const f32x4* __restrict__ x,
    const int* __restrict__ token_positions,
    f32x4* __restrict__ out,
    int n4)
{
    int T = n4 >> 2;                                  // total threads
    int t = blockIdx.x * blockDim.x + threadIdx.x;
    if (t >= T) return;

    // T % PERIOD_F4 == 0 (guarded in launcher), so t, t+T, t+2T, t+3T all map to
    // the same (s, pair-pair) -> one trig evaluation serves all 4 float4s.
    int s  = (t >> 5) & (SEQ - 1);    // sequence index within the slice
    int i0 = (t & 31) * 2;            // first pair index handled by this float4

    float p  = (float)token_positions[s];
    float f0 = exp2f(-THETA_LOG2_OVER_HALF * (float)i0);
    float f1 = f0 * FREQ_STEP;

    float a0 = p * f0, a1 = p * f1;
    float s0 = __sinf(a0), c0 = __cosf(a0);
    float s1 = __sinf(a1), c1 = __cosf(a1);

    // Issue all 4 nontemporal loads up front: 4 outstanding VMEM ops per lane.
    f32x4 v0 = __builtin_nontemporal_load(&x[t]);
    f32x4 v1 = __builtin_nontemporal_load(&x[t +     T]);
    f32x4 v2 = __builtin_nontemporal_load(&x[t + 2 * T]);
    f32x4 v3 = __builtin_nontemporal_load(&x[t + 3 * T]);

    f32x4 r;
    r.x = c0 * v0.x - s0 * v0.y;
    r.y = s0 * v0.x + c0 * v0.y;
    r.z = c1 * v0.z - s1 * v0.w;
    r.w = s1 * v0.z + c1 * v0.w;
    __builtin_nontemporal_store(r, &out[t]);

    r.x = c0 * v1.x - s0 * v1.y;
    r.y = s0 * v1.x + c0 * v1.y;
    r.z = c1 * v1.z - s1 * v1.w;
    r.w = s1 * v1.z + c1 * v1.w;
    __builtin_nontemporal_store(r, &out[t + T]);

    r.x = c0 * v2.x - s0 * v2.y;
    r.y = s0 * v2.x + c0 * v2.y;
    r.z = c1 * v2.z - s1 * v2.w;
    r.w = s1 * v2.z + c1 * v2.w;
    __builtin_nontemporal_store(r, &out[t + 2 * T]);

    r.x = c0 * v3.x - s0 * v3.y;
    r.y = s0 * v3.x + c0 * v3.y;
    r.z = c1 * v3.z - s1 * v3.w;
    r.w = s1 * v3.z + c1 * v3.w;
    __builtin_nontemporal_store(r, &out[t + 3 * T]);
}

// ---------------- Fallback: 1 float4/thread, inline trig ----------------
__global__ __launch_bounds__(256) void rope_f32_kernel(
    const float4* __restrict__ x,
    const int* __restrict__ token_positions,
    float4* __restrict__ out,
    int n4)
{
    int t = blockIdx.x * blockDim.x + threadIdx.x;
    if (t >= n4) return;

    int s  = (t >> 5) & (SEQ - 1);
    int i0 = (t & 31) * 2;

    float p  = (float)token_positions[s];
    float f0 = exp2f(-THETA_LOG2_OVER_HALF * (float)i0);
    float f1 = f0 * FREQ_STEP;

    float a0 = p * f0, a1 = p * f1;
    float s0 = __sinf(a0), c0 = __cosf(a0);
    float s1 = __sinf(a1), c1 = __cosf(a1);

    float4 v = x[t];
    float4 r;
    r.x = c0 * v.x - s0 * v.y;
    r.y = s0 * v.x + c0 * v.y;
    r.z = c1 * v.z - s1 * v.w;
    r.w = s1 * v.z + c1 * v.w;
    out[t] = r;
}

extern "C" void kernel_launch(void* const* d_in, const int* in_sizes, int n_in,
                              void* d_out, int out_size, void* d_ws, size_t ws_size,
                              hipStream_t stream) {
    const int* token_positions = (const int*)d_in[1];

    int n4 = out_size / 4;   // out_size is in floats; 16,777,216 float4s

    if ((n4 % (PERIOD_F4 * 4)) == 0) {
        int T = n4 >> 2;     // 4,194,304 threads; multiple of PERIOD_F4 and of 256
        rope_f32_x4_kernel<<<dim3(T / 256), dim3(256), 0, stream>>>(
            (const f32x4*)d_in[0], token_positions, (f32x4*)d_out, n4);
    } else {
        int grid = (n4 + 255) / 256;
        rope_f32_kernel<<<grid, dim3(256), 0, stream>>>(
            (const float4*)d_in[0], token_positions, (float4*)d_out, n4);
    }
}

// Round 4
// 416.081 us; speedup vs baseline: 1.0488x; 1.0488x over previous
//
#include <hip/hip_runtime.h>
#include <math.h>

// RoPE over x[4,32,4096,128] fp32, positions = token_positions[4096] (int32).
// Pairwise rotation on (even, odd) feature pairs:
//   out[2i]   = cos(a)*x[2i] - sin(a)*x[2i+1]
//   out[2i+1] = sin(a)*x[2i] + cos(a)*x[2i+1],  a = pos * theta^(-2i/128)
//
// v4 == v0 (deliberate revert). Session findings:
//   - v0 measured 415.15/415.7 us across two sessions; timing model
//     dur_us ~= 2 x 165us harness poison fills + ~85us kernel.
//   - Kernel floor: 512 MiB @ 6.5 TB/s (fill-demonstrated) = ~82.5 us -> v0 is
//     within ~3% of the achievable HBM ceiling.
//   - v2 (trig-table in d_ws): +20us. Trig is NOT the bottleneck (5 quarter-rate
//     trans ops per 32B of traffic = ~40x above HBM ceiling).
//   - v3 (4 float4/thread at 64MiB stride + nontemporal): +21us. The 8 distant
//     streams per wave degrade DRAM page locality; NT stores lose L2
//     write-combining. Plain 1-float4/thread contiguous streaming wins.
//
// One thread per float4 (2 pairs): coalesced 16B loads/stores.

#define THETA_LOG2_OVER_HALF 0.20762050593046013f   // log2(10000)/64
#define FREQ_STEP 0.8659643233600653f               // 10000^(-1/64)

__global__ __launch_bounds__(256) void rope_f32_kernel(
    const float4* __restrict__ x,
    const int* __restrict__ token_positions,
    float4* __restrict__ out,
    int n4)
{
    int t = blockIdx.x * blockDim.x + threadIdx.x;
    if (t >= n4) return;

    // 128 floats per row = 32 float4 per row; 4096 rows per (b,h) slice.
    int s  = (t >> 5) & 4095;     // sequence index within the slice
    int i0 = (t & 31) * 2;        // first pair index handled by this float4

    float p = (float)token_positions[s];

    // inv_freq(i0) and inv_freq(i0+1) = inv_freq(i0) * 10000^(-1/64)
    float f0 = exp2f(-THETA_LOG2_OVER_HALF * (float)i0);
    float f1 = f0 * FREQ_STEP;

    float a0 = p * f0;
    float a1 = p * f1;

    float s0 = __sinf(a0), c0 = __cosf(a0);
    float s1 = __sinf(a1), c1 = __cosf(a1);

    float4 v = x[t];
    float4 r;
    r.x = c0 * v.x - s0 * v.y;
    r.y = s0 * v.x + c0 * v.y;
    r.z = c1 * v.z - s1 * v.w;
    r.w = s1 * v.z + c1 * v.w;
    out[t] = r;
}

extern "C" void kernel_launch(void* const* d_in, const int* in_sizes, int n_in,
                              void* d_out, int out_size, void* d_ws, size_t ws_size,
                              hipStream_t stream) {
    const float* x = (const float*)d_in[0];
    const int* token_positions = (const int*)d_in[1];
    float* out = (float*)d_out;

    int n4 = out_size / 4;                 // 16,777,216 float4s
    int block = 256;
    int grid = (n4 + block - 1) / block;   // 65,536 blocks

    rope_f32_kernel<<<grid, block, 0, stream>>>(
        (const float4*)x, token_positions, (float4*)out, n4);
}